// Round 1
// baseline (670.527 us; speedup 1.0000x reference)
//
#include <hip/hip_runtime.h>
#include <hip/hip_bf16.h>

#define D 64
#define SCAN_B 1024

// ---------------- small GEMMs / setup ----------------

// embW[v][d] = sum_k emb[v][k] * W[k][d]   (V x D)
__global__ void embW_kernel(const float* __restrict__ emb, const float* __restrict__ W,
                            float* __restrict__ embW) {
    int v = blockIdx.x, lane = threadIdx.x;
    float e = emb[v * D + lane];
    float acc = 0.f;
#pragma unroll
    for (int k = 0; k < D; ++k)
        acc += __shfl(e, k) * W[k * D + lane];
    embW[v * D + lane] = acc;
}

// ---------------- CSR build ----------------

__global__ void deg_kernel(const int* __restrict__ dst, int* __restrict__ deg, int E) {
    int e = blockIdx.x * blockDim.x + threadIdx.x;
    if (e < E) atomicAdd(&deg[dst[e]], 1);
}

__global__ void scan1_kernel(const int* __restrict__ deg, int* __restrict__ rowptr,
                             int* __restrict__ bsum, int N) {
    __shared__ int lds[SCAN_B];
    int i = blockIdx.x * SCAN_B + threadIdx.x;
    int v = (i < N) ? deg[i] : 0;
    lds[threadIdx.x] = v;
    __syncthreads();
    for (int off = 1; off < SCAN_B; off <<= 1) {
        int t = (threadIdx.x >= (unsigned)off) ? lds[threadIdx.x - off] : 0;
        __syncthreads();
        lds[threadIdx.x] += t;
        __syncthreads();
    }
    if (i < N) rowptr[i + 1] = lds[threadIdx.x];
    if (threadIdx.x == SCAN_B - 1) bsum[blockIdx.x] = lds[threadIdx.x];
}

__global__ void scan2_kernel(int* __restrict__ bsum, int nb) {
    if (blockIdx.x == 0 && threadIdx.x == 0) {
        int acc = 0;
        for (int b = 0; b < nb; ++b) { int t = bsum[b]; bsum[b] = acc; acc += t; }
    }
}

__global__ void scan3_kernel(int* __restrict__ rowptr, const int* __restrict__ bsum, int N) {
    int i = blockIdx.x * blockDim.x + threadIdx.x;
    if (i == 0) rowptr[0] = 0;
    if (i < N) rowptr[i + 1] += bsum[i / SCAN_B];
}

__global__ void copy_cursor_kernel(const int* __restrict__ rowptr, int* __restrict__ cursor, int N) {
    int i = blockIdx.x * blockDim.x + threadIdx.x;
    if (i < N) cursor[i] = rowptr[i];
}

__global__ void fill_kernel(const int* __restrict__ src, const int* __restrict__ dst,
                            int* __restrict__ cursor, int* __restrict__ col, int E) {
    int e = blockIdx.x * blockDim.x + threadIdx.x;
    if (e >= E) return;
    int d = dst[e];
    int pos = atomicAdd(&cursor[d], 1);
    col[pos] = src[e];
}

// ---------------- GCN: h1[v] = relu( sum_{u in N_in(v)} embW[x[u]] ) ----------------

__global__ __launch_bounds__(256) void gcn_kernel(const int* __restrict__ rowptr,
                                                  const int* __restrict__ col,
                                                  const int* __restrict__ x,
                                                  const float* __restrict__ embW,
                                                  float* __restrict__ h1, int N, int V) {
    extern __shared__ float lembW[];  // V*D floats (32 KB for V=128)
    int tid = threadIdx.x;
    for (int i = tid; i < V * D; i += 256) lembW[i] = embW[i];
    __syncthreads();
    int wave = tid >> 6, lane = tid & 63;
    int v = blockIdx.x * 4 + wave;
    if (v >= N) return;
    int beg = rowptr[v], end = rowptr[v + 1];
    float acc = 0.f;
    for (int e = beg; e < end; ++e) {
        int u = col[e];
        int xu = x[u];
        acc += lembW[xu * D + lane];
    }
    h1[v * D + lane] = fmaxf(acc, 0.f);
}

// ---------------- generic neighbor aggregation (sum or mean) ----------------

__global__ __launch_bounds__(256) void agg_kernel(const int* __restrict__ rowptr,
                                                  const int* __restrict__ col,
                                                  const float* __restrict__ hin,
                                                  float* __restrict__ hout, int N, int do_mean) {
    int tid = threadIdx.x;
    int wave = tid >> 6, lane = tid & 63;
    int v = blockIdx.x * 4 + wave;
    if (v >= N) return;
    int beg = rowptr[v], end = rowptr[v + 1];
    float acc = 0.f;
    for (int e = beg; e < end; ++e) {
        int u = col[e];
        acc += hin[u * D + lane];
    }
    if (do_mean) acc *= (1.f / fmaxf((float)(end - beg), 1.f));
    hout[v * D + lane] = acc;
}

// ---------------- SAGE: h2 = relu( mean_nb @ Wl + h1 @ Wr ) ----------------

__global__ __launch_bounds__(256) void sage_kernel(const float* __restrict__ mean_nb,
                                                   const float* __restrict__ h1,
                                                   const float* __restrict__ Wl,
                                                   const float* __restrict__ Wr,
                                                   float* __restrict__ h2, int N) {
    __shared__ float lWl[D * D];
    __shared__ float lWr[D * D];
    int tid = threadIdx.x;
    for (int i = tid; i < D * D; i += 256) { lWl[i] = Wl[i]; lWr[i] = Wr[i]; }
    __syncthreads();
    int wave = tid >> 6, lane = tid & 63;
    int v = blockIdx.x * 4 + wave;
    if (v >= N) return;
    float m = mean_nb[v * D + lane];
    float r = h1[v * D + lane];
    float acc = 0.f;
#pragma unroll
    for (int k = 0; k < D; ++k) {
        acc += __shfl(m, k) * lWl[k * D + lane] + __shfl(r, k) * lWr[k * D + lane];
    }
    h2[v * D + lane] = fmaxf(acc, 0.f);
}

// ---------------- GIN: h3 = relu( relu((h2+agg)@W1 + b1) @ W2 + b2 ) ----------------

__global__ __launch_bounds__(256) void gin_kernel(const float* __restrict__ h2,
                                                  const float* __restrict__ agg,
                                                  const float* __restrict__ W1,
                                                  const float* __restrict__ b1,
                                                  const float* __restrict__ W2,
                                                  const float* __restrict__ b2,
                                                  float* __restrict__ h3, int N) {
    __shared__ float lW1[D * D];
    __shared__ float lW2[D * D];
    int tid = threadIdx.x;
    for (int i = tid; i < D * D; i += 256) { lW1[i] = W1[i]; lW2[i] = W2[i]; }
    __syncthreads();
    int wave = tid >> 6, lane = tid & 63;
    int v = blockIdx.x * 4 + wave;
    if (v >= N) return;
    int idx = v * D + lane;
    float z = h2[idx] + agg[idx];
    float acc1 = b1[lane];
#pragma unroll
    for (int k = 0; k < D; ++k)
        acc1 += __shfl(z, k) * lW1[k * D + lane];
    float t = fmaxf(acc1, 0.f);
    float acc2 = b2[lane];
#pragma unroll
    for (int k = 0; k < D; ++k)
        acc2 += __shfl(t, k) * lW2[k * D + lane];
    h3[idx] = fmaxf(acc2, 0.f);
}

// ---------------- pooling ----------------

__global__ void gstart_kernel(const int* __restrict__ batch, int* __restrict__ gstart, int N, int G) {
    int g = blockIdx.x * blockDim.x + threadIdx.x;
    if (g > G) return;
    int lo = 0, hi = N;
    while (lo < hi) {
        int mid = (lo + hi) >> 1;
        if (batch[mid] < g) lo = mid + 1; else hi = mid;
    }
    gstart[g] = lo;
}

__global__ void pool_kernel(const float* __restrict__ h1, const float* __restrict__ h2,
                            const float* __restrict__ h3, const int* __restrict__ gstart,
                            float* __restrict__ pm, int G) {
    int g = blockIdx.x;
    int lane = threadIdx.x;
    int beg = gstart[g], end = gstart[g + 1];
    float s1 = 0.f, s2 = 0.f, s3 = 0.f;
    for (int v = beg; v < end; ++v) {
        s1 += h1[v * D + lane];
        s2 += h2[v * D + lane];
        s3 += h3[v * D + lane];
    }
    float inv = 1.f / fmaxf((float)(end - beg), 1.f);
    pm[(0 * G + g) * D + lane] = s1 * inv;
    pm[(1 * G + g) * D + lane] = s2 * inv;
    pm[(2 * G + g) * D + lane] = s3 * inv;
}

__global__ void final_kernel(const float* __restrict__ pm,
                             const float* __restrict__ W1, const float* __restrict__ W2,
                             const float* __restrict__ W3, float* __restrict__ out, int G) {
    int g = blockIdx.x, lane = threadIdx.x;
    float p1 = pm[(0 * G + g) * D + lane];
    float p2 = pm[(1 * G + g) * D + lane];
    float p3 = pm[(2 * G + g) * D + lane];
    float acc = 0.f;
#pragma unroll
    for (int k = 0; k < D; ++k) {
        acc += __shfl(p1, k) * W1[k * D + lane]
             + __shfl(p2, k) * W2[k * D + lane]
             + __shfl(p3, k) * W3[k * D + lane];
    }
    out[g * D + lane] = fmaxf(acc, 0.f);
}

// ---------------- launch ----------------

static inline size_t align256(size_t x) { return (x + 255) & ~(size_t)255; }

extern "C" void kernel_launch(void* const* d_in, const int* in_sizes, int n_in,
                              void* d_out, int out_size, void* d_ws, size_t ws_size,
                              hipStream_t stream) {
    const int* x      = (const int*)d_in[0];
    const int* ei     = (const int*)d_in[1];
    const int* batch  = (const int*)d_in[2];
    const float* emb  = (const float*)d_in[3];
    const float* Wgcn = (const float*)d_in[4];
    const float* Wsl  = (const float*)d_in[5];
    const float* Wsr  = (const float*)d_in[6];
    const float* Wg1  = (const float*)d_in[7];
    const float* bg1  = (const float*)d_in[8];
    const float* Wg2  = (const float*)d_in[9];
    const float* bg2  = (const float*)d_in[10];
    const float* Wp1  = (const float*)d_in[11];
    const float* Wp2  = (const float*)d_in[12];
    const float* Wp3  = (const float*)d_in[13];
    float* out = (float*)d_out;

    const int N = in_sizes[0];
    const int E = in_sizes[1] / 2;
    const int V = in_sizes[3] / D;
    const int G = out_size / D;
    const int* src = ei;
    const int* dst = ei + E;

    const int NB = (N + SCAN_B - 1) / SCAN_B;

    // workspace layout
    char* base = (char*)d_ws;
    size_t off = 0;
    float* embW   = (float*)(base + off); off = align256(off + (size_t)V * D * 4);
    int*   deg    = (int*)(base + off);   off = align256(off + (size_t)N * 4);
    int*   rowptr = (int*)(base + off);   off = align256(off + (size_t)(N + 1) * 4);
    int*   cursor = (int*)(base + off);   off = align256(off + (size_t)N * 4);
    int*   bsum   = (int*)(base + off);   off = align256(off + (size_t)NB * 4);
    int*   gstart = (int*)(base + off);   off = align256(off + (size_t)(G + 1) * 4);
    int*   col    = (int*)(base + off);   off = align256(off + (size_t)E * 4);
    float* h1     = (float*)(base + off); off = align256(off + (size_t)N * D * 4);
    float* h2     = (float*)(base + off); off = align256(off + (size_t)N * D * 4);
    float* h3     = (float*)(base + off); off = align256(off + (size_t)N * D * 4);
    float* tmp    = (float*)(base + off); off = align256(off + (size_t)N * D * 4);
    float* pm     = (float*)(base + off); off = align256(off + (size_t)3 * G * D * 4);
    (void)ws_size;

    hipMemsetAsync(deg, 0, (size_t)N * 4, stream);

    embW_kernel<<<V, D, 0, stream>>>(emb, Wgcn, embW);

    int eb = (E + 255) / 256;
    deg_kernel<<<eb, 256, 0, stream>>>(dst, deg, E);
    scan1_kernel<<<NB, SCAN_B, 0, stream>>>(deg, rowptr, bsum, N);
    scan2_kernel<<<1, 64, 0, stream>>>(bsum, NB);
    int nb256 = (N + 255) / 256;
    scan3_kernel<<<nb256, 256, 0, stream>>>(rowptr, bsum, N);
    copy_cursor_kernel<<<nb256, 256, 0, stream>>>(rowptr, cursor, N);
    fill_kernel<<<eb, 256, 0, stream>>>(src, dst, cursor, col, E);

    int nodeb = (N + 3) / 4;
    gcn_kernel<<<nodeb, 256, (size_t)V * D * 4, stream>>>(rowptr, col, x, embW, h1, N, V);

    agg_kernel<<<nodeb, 256, 0, stream>>>(rowptr, col, h1, tmp, N, 1);       // mean_nb
    sage_kernel<<<nodeb, 256, 0, stream>>>(tmp, h1, Wsl, Wsr, h2, N);

    agg_kernel<<<nodeb, 256, 0, stream>>>(rowptr, col, h2, tmp, N, 0);       // gin agg
    gin_kernel<<<nodeb, 256, 0, stream>>>(h2, tmp, Wg1, bg1, Wg2, bg2, h3, N);

    gstart_kernel<<<1, 1024, 0, stream>>>(batch, gstart, N, G);
    pool_kernel<<<G, D, 0, stream>>>(h1, h2, h3, gstart, pm, G);
    final_kernel<<<G, D, 0, stream>>>(pm, Wp1, Wp2, Wp3, out, G);
}

// Round 2
// 386.594 us; speedup vs baseline: 1.7344x; 1.7344x over previous
//
#include <hip/hip_runtime.h>
#include <hip/hip_bf16.h>

#define D 64
#define SCAN_B 1024

// ================= register-tiled fp32 GEMM: out = act(in[nrows x 64] @ W + bias) =================
// Optional dual output (same input, two weight matrices). 64 rows per block, 256 threads,
// each thread computes a 4x4 register tile. W + A-tile staged in LDS.

__global__ __launch_bounds__(256) void gemm64_kernel(
    const float* __restrict__ in, int nrows,
    const float* __restrict__ W1, const float* __restrict__ W2,
    const float* __restrict__ bias, int do_relu,
    float* __restrict__ out1, float* __restrict__ out2)
{
    __shared__ float At[64][68];      // padded: rows 4 apart differ by 16 banks -> 2-way max (free)
    __shared__ float Ws1[64][64];
    __shared__ float Ws2[64][64];
    int tid = threadIdx.x;
    {
        const float4* w1v = (const float4*)W1;
        float4* s1 = (float4*)&Ws1[0][0];
        for (int i = tid; i < 1024; i += 256) s1[i] = w1v[i];
        if (W2) {
            const float4* w2v = (const float4*)W2;
            float4* s2 = (float4*)&Ws2[0][0];
            for (int i = tid; i < 1024; i += 256) s2[i] = w2v[i];
        }
    }
    int r0 = blockIdx.x * 64;
    for (int i = tid; i < 1024; i += 256) {
        int r = i >> 4, c4 = i & 15;
        int gr = r0 + r; if (gr >= nrows) gr = nrows - 1;   // clamp: safe dup read
        float4 v = ((const float4*)(in + (size_t)gr * D))[c4];
        float* dp = &At[r][c4 * 4];
        dp[0] = v.x; dp[1] = v.y; dp[2] = v.z; dp[3] = v.w;
    }
    __syncthreads();

    int cg = tid & 15;        // col group: cols 4*cg..4*cg+3
    int rg = tid >> 4;        // row group: rows 4*rg..4*rg+3
    float acc1[4][4] = {{0.f}}, acc2[4][4] = {{0.f}};

    for (int k0 = 0; k0 < 64; k0 += 4) {
        float4 a[4], w1[4];
#pragma unroll
        for (int i = 0; i < 4; ++i) a[i] = *(const float4*)&At[4 * rg + i][k0];
#pragma unroll
        for (int j = 0; j < 4; ++j) w1[j] = *(const float4*)&Ws1[k0 + j][cg * 4];
#pragma unroll
        for (int i = 0; i < 4; ++i) {
            float av[4] = {a[i].x, a[i].y, a[i].z, a[i].w};
#pragma unroll
            for (int kk = 0; kk < 4; ++kk) {
                acc1[i][0] += av[kk] * w1[kk].x;
                acc1[i][1] += av[kk] * w1[kk].y;
                acc1[i][2] += av[kk] * w1[kk].z;
                acc1[i][3] += av[kk] * w1[kk].w;
            }
        }
        if (W2) {
            float4 w2[4];
#pragma unroll
            for (int j = 0; j < 4; ++j) w2[j] = *(const float4*)&Ws2[k0 + j][cg * 4];
#pragma unroll
            for (int i = 0; i < 4; ++i) {
                float av[4] = {a[i].x, a[i].y, a[i].z, a[i].w};
#pragma unroll
                for (int kk = 0; kk < 4; ++kk) {
                    acc2[i][0] += av[kk] * w2[kk].x;
                    acc2[i][1] += av[kk] * w2[kk].y;
                    acc2[i][2] += av[kk] * w2[kk].z;
                    acc2[i][3] += av[kk] * w2[kk].w;
                }
            }
        }
    }

    float4 bv = make_float4(0.f, 0.f, 0.f, 0.f);
    if (bias) bv = ((const float4*)bias)[cg];
#pragma unroll
    for (int i = 0; i < 4; ++i) {
        int gr = r0 + 4 * rg + i;
        if (gr < nrows) {
            float4 o;
            o.x = acc1[i][0] + bv.x; o.y = acc1[i][1] + bv.y;
            o.z = acc1[i][2] + bv.z; o.w = acc1[i][3] + bv.w;
            if (do_relu) {
                o.x = fmaxf(o.x, 0.f); o.y = fmaxf(o.y, 0.f);
                o.z = fmaxf(o.z, 0.f); o.w = fmaxf(o.w, 0.f);
            }
            ((float4*)(out1 + (size_t)gr * D))[cg] = o;
            if (out2) {
                float4 o2;
                o2.x = acc2[i][0]; o2.y = acc2[i][1]; o2.z = acc2[i][2]; o2.w = acc2[i][3];
                ((float4*)(out2 + (size_t)gr * D))[cg] = o2;
            }
        }
    }
}

// ================= CSR build =================

__global__ void deg_kernel(const int* __restrict__ dst, int* __restrict__ deg, int E) {
    int e = blockIdx.x * blockDim.x + threadIdx.x;
    if (e < E) atomicAdd(&deg[dst[e]], 1);
}

__global__ void scan1_kernel(const int* __restrict__ deg, int* __restrict__ rowptr,
                             int* __restrict__ bsum, int N) {
    __shared__ int lds[SCAN_B];
    int i = blockIdx.x * SCAN_B + threadIdx.x;
    int v = (i < N) ? deg[i] : 0;
    lds[threadIdx.x] = v;
    __syncthreads();
    for (int off = 1; off < SCAN_B; off <<= 1) {
        int t = (threadIdx.x >= (unsigned)off) ? lds[threadIdx.x - off] : 0;
        __syncthreads();
        lds[threadIdx.x] += t;
        __syncthreads();
    }
    if (i < N) rowptr[i + 1] = lds[threadIdx.x];
    if (threadIdx.x == SCAN_B - 1) bsum[blockIdx.x] = lds[threadIdx.x];
}

// single-wave exclusive scan of bsum (nb can exceed 64: chunked with carry)
__global__ void scan2_kernel(int* __restrict__ bsum, int nb) {
    int lane = threadIdx.x;  // 64 threads
    int carry = 0;
    for (int base = 0; base < nb; base += 64) {
        int i = base + lane;
        int orig = (i < nb) ? bsum[i] : 0;
        int v = orig;
        for (int off = 1; off < 64; off <<= 1) {
            int t = __shfl_up(v, off);
            if (lane >= off) v += t;
        }
        if (i < nb) bsum[i] = carry + v - orig;  // exclusive
        carry += __shfl(v, 63);
    }
}

__global__ void scan3_kernel(int* __restrict__ rowptr, int* __restrict__ cursor,
                             const int* __restrict__ bsum, int N) {
    int i = blockIdx.x * blockDim.x + threadIdx.x;
    if (i == 0) { rowptr[0] = 0; cursor[0] = 0; }
    if (i < N) {
        int v = rowptr[i + 1] + bsum[i / SCAN_B];
        rowptr[i + 1] = v;
        if (i + 1 < N) cursor[i + 1] = v;
    }
}

__global__ void fill_kernel(const int* __restrict__ src, const int* __restrict__ dst,
                            const int* __restrict__ x, int* __restrict__ cursor,
                            int* __restrict__ col, int* __restrict__ xcol, int E) {
    int e = blockIdx.x * blockDim.x + threadIdx.x;
    if (e >= E) return;
    int d = dst[e];
    int s = src[e];
    int pos = atomicAdd(&cursor[d], 1);
    col[pos] = s;
    xcol[pos] = x[s];
}

// ================= GCN: h1[v] = relu( sum_{u in N_in(v)} embW[x[u]] ) =================
// grid-stride over nodes to amortize the 32KB LDS staging of embW.

__global__ __launch_bounds__(256) void gcn_kernel(const int* __restrict__ rowptr,
                                                  const int* __restrict__ xcol,
                                                  const float* __restrict__ embW,
                                                  float* __restrict__ h1, int N, int V) {
    extern __shared__ float lembW[];
    int tid = threadIdx.x;
    for (int i = tid; i < V * D; i += 256) lembW[i] = embW[i];
    __syncthreads();
    int lane = tid & 63;
    int wid = (blockIdx.x * 256 + tid) >> 6;
    int stride = (gridDim.x * 256) >> 6;
    for (int v = wid; v < N; v += stride) {
        int beg = rowptr[v], end = rowptr[v + 1];
        float acc = 0.f;
        int e = beg;
        for (; e + 4 <= end; e += 4) {
            int u0 = xcol[e], u1 = xcol[e + 1], u2 = xcol[e + 2], u3 = xcol[e + 3];
            float f0 = lembW[u0 * D + lane];
            float f1 = lembW[u1 * D + lane];
            float f2 = lembW[u2 * D + lane];
            float f3 = lembW[u3 * D + lane];
            acc += f0; acc += f1; acc += f2; acc += f3;
        }
        for (; e < end; ++e) acc += lembW[xcol[e] * D + lane];
        h1[(size_t)v * D + lane] = fmaxf(acc, 0.f);
    }
}

// ================= SAGE epilogue: h2 = relu( agg(A)/deg + B ),  A=h1@Wl, B=h1@Wr =================

__global__ __launch_bounds__(256) void sage_agg_kernel(const int* __restrict__ rowptr,
                                                       const int* __restrict__ col,
                                                       const float* __restrict__ A,
                                                       const float* __restrict__ B,
                                                       float* __restrict__ h2, int N) {
    int tid = threadIdx.x;
    int lane = tid & 63;
    int v = blockIdx.x * 4 + (tid >> 6);
    if (v >= N) return;
    int beg = rowptr[v], end = rowptr[v + 1];
    float acc = 0.f;
    int e = beg;
    for (; e + 4 <= end; e += 4) {
        int u0 = col[e], u1 = col[e + 1], u2 = col[e + 2], u3 = col[e + 3];
        float f0 = A[(size_t)u0 * D + lane];
        float f1 = A[(size_t)u1 * D + lane];
        float f2 = A[(size_t)u2 * D + lane];
        float f3 = A[(size_t)u3 * D + lane];
        acc += f0; acc += f1; acc += f2; acc += f3;
    }
    for (; e < end; ++e) acc += A[(size_t)col[e] * D + lane];
    float inv = 1.f / fmaxf((float)(end - beg), 1.f);
    h2[(size_t)v * D + lane] = fmaxf(acc * inv + B[(size_t)v * D + lane], 0.f);
}

// ================= GIN epilogue: t = relu( C + agg(C) + b1 ),  C=h2@W1 =================

__global__ __launch_bounds__(256) void gin_agg_kernel(const int* __restrict__ rowptr,
                                                      const int* __restrict__ col,
                                                      const float* __restrict__ C,
                                                      const float* __restrict__ b1,
                                                      float* __restrict__ t, int N) {
    int tid = threadIdx.x;
    int lane = tid & 63;
    int v = blockIdx.x * 4 + (tid >> 6);
    if (v >= N) return;
    int beg = rowptr[v], end = rowptr[v + 1];
    float acc = 0.f;
    int e = beg;
    for (; e + 4 <= end; e += 4) {
        int u0 = col[e], u1 = col[e + 1], u2 = col[e + 2], u3 = col[e + 3];
        float f0 = C[(size_t)u0 * D + lane];
        float f1 = C[(size_t)u1 * D + lane];
        float f2 = C[(size_t)u2 * D + lane];
        float f3 = C[(size_t)u3 * D + lane];
        acc += f0; acc += f1; acc += f2; acc += f3;
    }
    for (; e < end; ++e) acc += C[(size_t)col[e] * D + lane];
    size_t idx = (size_t)v * D + lane;
    t[idx] = fmaxf(C[idx] + acc + b1[lane], 0.f);
}

// ================= pooling =================

__global__ void gstart_kernel(const int* __restrict__ batch, int* __restrict__ gstart, int N, int G) {
    int g = blockIdx.x * blockDim.x + threadIdx.x;
    if (g > G) return;
    int lo = 0, hi = N;
    while (lo < hi) {
        int mid = (lo + hi) >> 1;
        if (batch[mid] < g) lo = mid + 1; else hi = mid;
    }
    gstart[g] = lo;
}

__global__ void pool_final_kernel(const float* __restrict__ h1, const float* __restrict__ h2,
                                  const float* __restrict__ h3, const int* __restrict__ gstart,
                                  const float* __restrict__ W1, const float* __restrict__ W2,
                                  const float* __restrict__ W3, float* __restrict__ out, int G) {
    int g = blockIdx.x;
    int lane = threadIdx.x;  // 64
    int beg = gstart[g], end = gstart[g + 1];
    float s1 = 0.f, s2 = 0.f, s3 = 0.f;
    for (int v = beg; v < end; ++v) {
        s1 += h1[(size_t)v * D + lane];
        s2 += h2[(size_t)v * D + lane];
        s3 += h3[(size_t)v * D + lane];
    }
    float inv = 1.f / fmaxf((float)(end - beg), 1.f);
    float p1 = s1 * inv, p2 = s2 * inv, p3 = s3 * inv;
    float acc = 0.f;
#pragma unroll
    for (int k = 0; k < D; ++k) {
        acc += __shfl(p1, k) * W1[k * D + lane]
             + __shfl(p2, k) * W2[k * D + lane]
             + __shfl(p3, k) * W3[k * D + lane];
    }
    out[(size_t)g * D + lane] = fmaxf(acc, 0.f);
}

// ================= launch =================

static inline size_t align256(size_t x) { return (x + 255) & ~(size_t)255; }

extern "C" void kernel_launch(void* const* d_in, const int* in_sizes, int n_in,
                              void* d_out, int out_size, void* d_ws, size_t ws_size,
                              hipStream_t stream) {
    const int* x      = (const int*)d_in[0];
    const int* ei     = (const int*)d_in[1];
    const int* batch  = (const int*)d_in[2];
    const float* emb  = (const float*)d_in[3];
    const float* Wgcn = (const float*)d_in[4];
    const float* Wsl  = (const float*)d_in[5];
    const float* Wsr  = (const float*)d_in[6];
    const float* Wg1  = (const float*)d_in[7];
    const float* bg1  = (const float*)d_in[8];
    const float* Wg2  = (const float*)d_in[9];
    const float* bg2  = (const float*)d_in[10];
    const float* Wp1  = (const float*)d_in[11];
    const float* Wp2  = (const float*)d_in[12];
    const float* Wp3  = (const float*)d_in[13];
    float* out = (float*)d_out;

    const int N = in_sizes[0];
    const int E = in_sizes[1] / 2;
    const int V = in_sizes[3] / D;
    const int G = out_size / D;
    const int* src = ei;
    const int* dst = ei + E;

    const int NB = (N + SCAN_B - 1) / SCAN_B;

    // workspace layout
    char* base = (char*)d_ws;
    size_t off = 0;
    float* embW   = (float*)(base + off); off = align256(off + (size_t)V * D * 4);
    int*   deg    = (int*)(base + off);   off = align256(off + (size_t)N * 4);
    int*   rowptr = (int*)(base + off);   off = align256(off + (size_t)(N + 1) * 4);
    int*   cursor = (int*)(base + off);   off = align256(off + (size_t)N * 4);
    int*   bsum   = (int*)(base + off);   off = align256(off + (size_t)NB * 4);
    int*   gstart = (int*)(base + off);   off = align256(off + (size_t)(G + 1) * 4);
    int*   col    = (int*)(base + off);   off = align256(off + (size_t)E * 4);
    int*   xcol   = (int*)(base + off);   off = align256(off + (size_t)E * 4);
    float* h1     = (float*)(base + off); off = align256(off + (size_t)N * D * 4);
    float* h2     = (float*)(base + off); off = align256(off + (size_t)N * D * 4);
    float* h3     = (float*)(base + off); off = align256(off + (size_t)N * D * 4);
    float* A      = (float*)(base + off); off = align256(off + (size_t)N * D * 4);
    float* B      = (float*)(base + off); off = align256(off + (size_t)N * D * 4);
    (void)ws_size;

    float* C = A;   // reuse: A dead after sage_agg
    float* t = B;   // reuse: B dead after sage_agg

    hipMemsetAsync(deg, 0, (size_t)N * 4, stream);

    // embW = emb @ Wgcn
    gemm64_kernel<<<(V + 63) / 64, 256, 0, stream>>>(emb, V, Wgcn, nullptr, nullptr, 0, embW, nullptr);

    int eb = (E + 255) / 256;
    deg_kernel<<<eb, 256, 0, stream>>>(dst, deg, E);
    scan1_kernel<<<NB, SCAN_B, 0, stream>>>(deg, rowptr, bsum, N);
    scan2_kernel<<<1, 64, 0, stream>>>(bsum, NB);
    int nb256 = (N + 255) / 256;
    scan3_kernel<<<nb256, 256, 0, stream>>>(rowptr, cursor, bsum, N);
    fill_kernel<<<eb, 256, 0, stream>>>(src, dst, x, cursor, col, xcol, E);

    // GCN gather
    gcn_kernel<<<2048, 256, (size_t)V * D * 4, stream>>>(rowptr, xcol, embW, h1, N, V);

    // SAGE: A = h1@Wl, B = h1@Wr (dual GEMM), then fused agg epilogue
    int gb = (N + 63) / 64;
    gemm64_kernel<<<gb, 256, 0, stream>>>(h1, N, Wsl, Wsr, nullptr, 0, A, B);
    sage_agg_kernel<<<(N + 3) / 4, 256, 0, stream>>>(rowptr, col, A, B, h2, N);

    // GIN: C = h2@W1, t = relu(C + agg(C) + b1), h3 = relu(t@W2 + b2)
    gemm64_kernel<<<gb, 256, 0, stream>>>(h2, N, Wg1, nullptr, nullptr, 0, C, nullptr);
    gin_agg_kernel<<<(N + 3) / 4, 256, 0, stream>>>(rowptr, col, C, bg1, t, N);
    gemm64_kernel<<<gb, 256, 0, stream>>>(t, N, Wg2, nullptr, bg2, 1, h3, nullptr);

    // pooling
    gstart_kernel<<<1, 1024, 0, stream>>>(batch, gstart, N, G);
    pool_final_kernel<<<G, D, 0, stream>>>(h1, h2, h3, gstart, Wp1, Wp2, Wp3, out, G);
}